// Round 1
// baseline (44.482 us; speedup 1.0000x reference)
//
#include <hip/hip_runtime.h>
#include <hip/hip_bf16.h>

#define BS  32
#define J   4
#define L   512
#define D   768
#define K   4
#define OUT 256
// num blocks = BS*J*K = 512, blk = b*16 + j*4 + k  (matches reshape order)

__global__ __launch_bounds__(256) void entity_fused_kernel(
    const float* __restrict__ Z,     // [BS, J, L, D]
    const int*   __restrict__ sep,   // [BS, J, K]
    const float* __restrict__ W,     // [D, OUT]
    const float* __restrict__ bias,  // [OUT]
    float*       __restrict__ out)   // [BS, J*K, OUT]
{
    const int blk = blockIdx.x;          // 0..511
    const int b   = blk >> 4;
    const int j   = (blk >> 2) & 3;
    const int k   = blk & 3;
    const int tid = threadIdx.x;

    const int sbase = (b * J + j) * K;
    const int end   = sep[sbase + k];
    const int start = (k == 0) ? 1 : (sep[sbase + k - 1] + 1);
    const float inv = 1.0f / (float)(end - start);

    const float* zrow = Z + ((size_t)(b * J + j) * L) * D;

    // ---- span mean-pool: thread t owns dims {t, t+256, t+512} ----
    float acc0 = 0.f, acc1 = 0.f, acc2 = 0.f;
    for (int l = start; l < end; ++l) {
        const float* r = zrow + (size_t)l * D;
        acc0 += r[tid];
        acc1 += r[tid + 256];
        acc2 += r[tid + 512];
    }

    __shared__ float pooled[D];
    pooled[tid]       = acc0 * inv;
    pooled[tid + 256] = acc1 * inv;
    pooled[tid + 512] = acc2 * inv;
    __syncthreads();

    // ---- linear: out[blk, tid] = bias[tid] + sum_d pooled[d] * W[d, tid] ----
    float o = bias[tid];
    #pragma unroll 8
    for (int d = 0; d < D; ++d) {
        o += pooled[d] * W[(size_t)d * OUT + tid];   // LDS broadcast * coalesced load
    }
    out[(size_t)blk * OUT + tid] = o;
}

extern "C" void kernel_launch(void* const* d_in, const int* in_sizes, int n_in,
                              void* d_out, int out_size, void* d_ws, size_t ws_size,
                              hipStream_t stream) {
    const float* Z    = (const float*)d_in[0];
    const int*   sep  = (const int*)d_in[1];
    const float* W    = (const float*)d_in[2];
    const float* bias = (const float*)d_in[3];
    float*       out  = (float*)d_out;

    entity_fused_kernel<<<BS * J * K, 256, 0, stream>>>(Z, sep, W, bias, out);
}